// Round 16
// baseline (74.394 us; speedup 1.0000x reference)
//
#include <hip/hip_runtime.h>
#include <math.h>

typedef unsigned int u32;
typedef unsigned short u16;
typedef __attribute__((ext_vector_type(4))) u32 u32x4;
typedef __attribute__((ext_vector_type(8))) short bf16x8;
typedef __attribute__((ext_vector_type(4))) float f32x4;

#define FDIM 76
#define NCELL 5776
#define NA 3
#define NCH 85
#define NCLS 80
#define KLAB 40
#define NB 16
#define CIN 256
#define TILES_PER_B 91
#define NBLK (NB * TILES_PER_B)   // 1456
#define CS_LD 68                  // Csb row stride in u16

typedef __attribute__((address_space(1))) const void gvoid_t;
typedef __attribute__((address_space(3))) void svoid_t;

// fast-math helpers (epilogue; tolerance is 2% of 2.4e5)
__device__ __forceinline__ float sigmf_(float x) { return __frcp_rn(1.0f + __expf(-x)); }
__device__ __forceinline__ float bce_fullf(float p, float t) {
    return -(t * fmaxf(__logf(p), -100.0f) + (1.0f - t) * fmaxf(__logf(1.0f - p), -100.0f));
}
__device__ __forceinline__ float bce1f(float p) { return -fmaxf(__logf(p), -100.0f); }
__device__ __forceinline__ float bce0f(float p) { return -fmaxf(__logf(1.0f - p), -100.0f); }

__device__ __forceinline__ u16 bf16rne(float f) {
    u32 u = __float_as_uint(f);
    u32 r = u + 0x7fffu + ((u >> 16) & 1u);
    return (u16)(r >> 16);
}
__device__ __forceinline__ float bf16f(u16 v) { return __uint_as_float(((u32)v) << 16); }

// ---- prep: W fp32->bf16 (blocks 0..255) + label records (block 256) ----
// lrec layout[16]: 0 ttlx 1 ttly 2 tbrx 3 tbry | 4 area 5 valid 6 key 7 scale |
//                  8 tvx 9 tvy 10 tlw 11 tlh | 12 cls 13-15 pad
__global__ __launch_bounds__(256) void yolo_prep(const float* __restrict__ W,
                                                 const float* __restrict__ labels,
                                                 u16* __restrict__ Wbf,
                                                 float* __restrict__ lrec) {
    if (blockIdx.x < 256) {
        int idx = blockIdx.x * 256 + threadIdx.x;
        int row = idx >> 8, col = idx & 255;
        float v = (row < NA * NCH) ? W[row * CIN + col] : 0.0f;
        Wbf[idx] = bf16rne(v);
        return;
    }
    for (int idx = threadIdx.x; idx < NB * KLAB; idx += 256) {
        const float* l = labels + idx * 5;
        float cls = l[0], x = l[1], y = l[2], ww = l[3], hh = l[4];
        bool valid = (cls + x + y + ww + hh) > 0.0f;
        float tx = x * FDIM, ty = y * FDIM, tw = ww * FDIM, th = hh * FDIM;
        int ti = (int)tx, tj = (int)ty;
        float area_a = (tw - tx) * (th - ty);
        const float aw[9] = {1.25f, 2.0f, 4.125f, 3.75f, 7.75f, 7.375f, 14.5f, 19.5f, 46.625f};
        const float ah[9] = {1.625f, 3.75f, 2.875f, 7.625f, 5.625f, 14.875f, 11.25f, 24.75f, 40.75f};
        float best = -1e30f;
        int bi = 0;
        for (int n = 0; n < 9; n++) {
            float bw = fminf(tw, aw[n]), bh = fminf(th, ah[n]);
            float ai = ((tx < bw) && (ty < bh)) ? (bw - tx) * (bh - ty) : 0.0f;
            float iou = valid ? ai / (area_a + aw[n] * ah[n] - ai) : -1.0f;
            if (iou > best) { best = iou; bi = n; }
        }
        int bn = bi % 3;
        bool assign = valid && (bi < 3);
        float* r = lrec + idx * 16;
        r[0] = tx - 0.5f * tw; r[1] = ty - 0.5f * th;
        r[2] = tx + 0.5f * tw; r[3] = ty + 0.5f * th;
        r[4] = tw * th;
        r[5] = valid ? 1.0f : 0.0f;
        r[6] = assign ? (float)((bn * FDIM + tj) * FDIM + ti) : -1.0f;
        r[7] = sqrtf(2.0f - tw * th / (float)(FDIM * FDIM));
        r[8] = tx - (float)ti; r[9] = ty - (float)tj;
        r[10] = logf(tw / aw[bn] + 1e-16f); r[11] = logf(th / ah[bn] + 1e-16f);
        r[12] = cls; r[13] = 0.0f; r[14] = 0.0f; r[15] = 0.0f;
    }
}

// ---- fused GEMM+loss: R14 counted-vmcnt pipeline + 16B DMA + split label scan ----
__global__ __launch_bounds__(512, 6) void yolo_mfma(const float* __restrict__ xin,
                                                    const u16* __restrict__ Wbf,
                                                    const float* __restrict__ bias,
                                                    const float* __restrict__ lrec,
                                                    float* __restrict__ partials) {
    // [0,16384) S0 fp32 [64k][64c] ; [16384,32768) S1 ; [32768,40960) A bf16 [64c][64k] swz
    // epilogue: Csb [256][68] bf16 aliases [0,34816) ; mrg[2][192][2] at 34816 (3072B) ;
    //           red[8][8] at 40704
    __shared__ char smem[40960];
    float* S0  = (float*)smem;
    float* S1  = (float*)(smem + 16384);
    u16*   A   = (u16*)(smem + 32768);
    u16*   Csb = (u16*)smem;
    float* mrg = (float*)(smem + 34816);   // [2][192][2]
    float* red = (float*)(smem + 40704);

    const int blk = blockIdx.x;
    const int b = blk / TILES_PER_B;
    const int tile = blk - b * TILES_PER_B;
    const int cell0 = tile * 64;
    const int t = threadIdx.x;
    const int lane = t & 63;
    const int wid = t >> 6;             // 0..7
    const int g = lane >> 4;
    const int l15 = lane & 15;

    const float* xbase = xin + (size_t)b * CIN * NCELL;
    const float* lb = lrec + b * KLAB * 16;          // wave-uniform label records (global)

    // 16B-DMA lane mapping: lane = (q,r), q=plane offset 0..3, r=cell quad 0..15
    const int q = lane >> 4;
    const int r4 = (lane & 15) * 4;
    int cq = cell0 + r4;
    if (cq > NCELL - 4) cq = NCELL - 4;  // clamp; garbage cells masked in epilogue

    // ---- DMA chunk 0 -> S0 (2 insts/wave, 16B/lane, fire-and-forget) ----
#pragma unroll
    for (int i = 0; i < 2; i++) {
        const int k0 = wid * 8 + i * 4;              // covers planes k0..k0+3
        __builtin_amdgcn_global_load_lds(
            (gvoid_t*)(xbase + (size_t)(k0 + q) * NCELL + cq),
            (svoid_t*)(S0 + k0 * 64), 16, 0, 0);
    }

    f32x4 acc[2][4];
#pragma unroll
    for (int mi = 0; mi < 2; mi++)
#pragma unroll
        for (int ni = 0; ni < 4; ni++) acc[mi][ni] = (f32x4){0.f, 0.f, 0.f, 0.f};

    const u16* wrow = Wbf + (wid * 32 + l15) * CIN;   // wave owns channels wid*32..+31

#pragma unroll
    for (int c = 0; c < 4; c++) {
        float* Sc = (c & 1) ? S1 : S0;
        // phase 1a: W fragments for THIS chunk (before next DMA -> drained by vmcnt(2))
        bf16x8 af[4];
#pragma unroll
        for (int s2 = 0; s2 < 2; s2++)
#pragma unroll
            for (int mi = 0; mi < 2; mi++)
                af[s2 * 2 + mi] = *(const bf16x8*)(wrow + mi * 16 * CIN + c * 64 + s2 * 32 + g * 8);
        // phase 1b: issue NEXT chunk's DMA (stays in flight across the barrier)
        if (c < 3) {
            float* Sn = (c & 1) ? S0 : S1;
#pragma unroll
            for (int i = 0; i < 2; i++) {
                const int k0 = wid * 8 + i * 4;
                __builtin_amdgcn_global_load_lds(
                    (gvoid_t*)(xbase + (size_t)((c + 1) * 64 + k0 + q) * NCELL + cq),
                    (svoid_t*)(Sn + k0 * 64), 16, 0, 0);
            }
            // drain this chunk's 2 DMA + 4 af; leave next chunk's 2 in flight
            asm volatile("s_waitcnt vmcnt(2) lgkmcnt(0)" ::: "memory");
        } else {
            asm volatile("s_waitcnt vmcnt(0) lgkmcnt(0)" ::: "memory");
        }
        __builtin_amdgcn_sched_barrier(0);
        __builtin_amdgcn_s_barrier();
        __builtin_amdgcn_sched_barrier(0);
        // phase 2: convert S[c] fp32 -> A bf16 [64c][64k] swizzled (each elem once)
        {
            const float* sp = Sc + wid * 8 * 64 + lane;   // k = wid*8+e, cell = lane
            u32x4 v;
#pragma unroll
            for (int e = 0; e < 4; e++) {
                float f0 = sp[(2 * e) * 64];
                float f1 = sp[(2 * e + 1) * 64];
                v[e] = (u32)bf16rne(f0) | ((u32)bf16rne(f1) << 16);
            }
            const int byte = (lane * 128 + wid * 16) ^ ((lane & 7) << 4);
            *(u32x4*)((char*)A + byte) = v;
        }
        asm volatile("s_waitcnt lgkmcnt(0)" ::: "memory");
        __builtin_amdgcn_sched_barrier(0);
        __builtin_amdgcn_s_barrier();
        __builtin_amdgcn_sched_barrier(0);
        // phase 3: 8 ds_read_b128 + 16 MFMA (no barrier; next iter's wait covers reads)
#pragma unroll
        for (int s2 = 0; s2 < 2; s2++) {
#pragma unroll
            for (int ni = 0; ni < 4; ni++) {
                const int cell = ni * 16 + l15;
                const int byte = (cell * 128 + s2 * 64 + g * 16) ^ ((cell & 7) << 4);
                bf16x8 bfr = *(const bf16x8*)((char*)A + byte);
                acc[0][ni] = __builtin_amdgcn_mfma_f32_16x16x32_bf16(af[s2 * 2 + 0], bfr, acc[0][ni], 0, 0, 0);
                acc[1][ni] = __builtin_amdgcn_mfma_f32_16x16x32_bf16(af[s2 * 2 + 1], bfr, acc[1][ni], 0, 0, 0);
            }
        }
    }

    __syncthreads();    // full drain before Csb aliases S0

    // bias for this thread's 8 output channels
    float bv[8];
#pragma unroll
    for (int mi = 0; mi < 2; mi++)
#pragma unroll
        for (int reg = 0; reg < 4; reg++) {
            const int ch = wid * 32 + mi * 16 + g * 4 + reg;
            bv[mi * 4 + reg] = (ch < NA * NCH) ? bias[ch] : 0.0f;
        }
    // C (+bias) -> LDS bf16 [256][CS_LD]
#pragma unroll
    for (int mi = 0; mi < 2; mi++)
#pragma unroll
        for (int ni = 0; ni < 4; ni++)
#pragma unroll
            for (int reg = 0; reg < 4; reg++) {
                const int ch = wid * 32 + mi * 16 + g * 4 + reg;
                const int cell = ni * 16 + l15;
                Csb[ch * CS_LD + cell] = bf16rne(acc[mi][ni][reg] + bv[mi * 4 + reg]);
            }
    __syncthreads();

    // ---- loss epilogue: phase A = split scan (half0: k<20, half1: k>=20), merge, phase B ----
    float part[5] = {0.f, 0.f, 0.f, 0.f, 0.f};
    const int half = (t >= 192) ? 1 : 0;
    const int unit = t - half * 192;
    bool active = false;
    float v0 = 0.f, v1 = 0.f, v2 = 0.f, v3 = 0.f, v4 = 0.f;
    float s0 = 0.f, s1 = 0.f, s4 = 0.f;
    float mIoU = -1e30f;
    int aidxp = -1;
    int a = 0, cc_ = 0, hh = 0, ww = 0, chb = 0;
    float mykey = 0.f;

    if (t < 384) {
        a = unit >> 6;
        cc_ = unit & 63;
        const int cgl = cell0 + cc_;
        if (cgl < NCELL) {
            active = true;
            chb = a * NCH;
            hh = cgl / FDIM;
            ww = cgl - hh * FDIM;
            mykey = (float)((a * FDIM + hh) * FDIM + ww);
            v0 = bf16f(Csb[(chb + 0) * CS_LD + cc_]);
            v1 = bf16f(Csb[(chb + 1) * CS_LD + cc_]);
            v2 = bf16f(Csb[(chb + 2) * CS_LD + cc_]);
            v3 = bf16f(Csb[(chb + 3) * CS_LD + cc_]);
            v4 = bf16f(Csb[(chb + 4) * CS_LD + cc_]);
            const float manw[3] = {1.25f, 2.0f, 4.125f};
            const float manh[3] = {1.625f, 3.75f, 2.875f};
            s0 = sigmf_(v0); s1 = sigmf_(v1); s4 = sigmf_(v4);
            float pw = __expf(v2) * manw[a];
            float ph = __expf(v3) * manh[a];
            float px = s0 + (float)ww, py = s1 + (float)hh;
            float parea = pw * ph;
            float ptlx = px - 0.5f * pw, ptly = py - 0.5f * ph;
            float pbrx = px + 0.5f * pw, pbry = py + 0.5f * ph;
            const float* lbh = lb + half * 20 * 16;
            for (int k = 0; k < 20; k++) {
                const f32x4 Aq = *(const f32x4*)(lbh + k * 16);
                const f32x4 Bq = *(const f32x4*)(lbh + k * 16 + 4);
                float tlx = fmaxf(ptlx, Aq.x), tly = fmaxf(ptly, Aq.y);
                float brx = fminf(pbrx, Aq.z), bry = fminf(pbry, Aq.w);
                float inter = ((tlx < brx) && (tly < bry)) ? (brx - tlx) * (bry - tly) : 0.0f;
                float iou = (Bq.y != 0.0f) ? inter * __frcp_rn(parea + Bq.x - inter) : 0.0f;
                mIoU = fmaxf(mIoU, iou);
                if (Bq.z == mykey) aidxp = half * 20 + k;   // last match wins (within half)
            }
        }
        mrg[(half * 192 + unit) * 2 + 0] = mIoU;
        mrg[(half * 192 + unit) * 2 + 1] = (float)aidxp;
    }
    __syncthreads();   // merge barrier (all 512 threads)

    if (t < 384 && active) {
        const float oIoU = mrg[((1 - half) * 192 + unit) * 2 + 0];
        const int oaidx = (int)mrg[((1 - half) * 192 + unit) * 2 + 1];
        const float maxiou = fmaxf(mIoU, oIoU);
        const int aidx = (aidxp > oaidx) ? aidxp : oaidx;   // last match wins (global)

        if (half == 0) {
            if (aidx >= 0) {
                const f32x4 Bq = *(const f32x4*)(lb + aidx * 16 + 4);
                const f32x4 Tv = *(const f32x4*)(lb + aidx * 16 + 8);
                float sc = Bq.w, sc2 = sc * sc;
                part[0] += sc2 * (bce_fullf(s0, Tv.x) + bce_fullf(s1, Tv.y));
                float dw = v2 - Tv.z, dh = v3 - Tv.w;
                float whq = dw * dw + dh * dh;
                part[1] += 0.5f * sc2 * whq;
                part[2] += bce1f(s4);
                int ci = (int)lb[aidx * 16 + 12];
                float l2 = (s0 - Tv.x) * (s0 - Tv.x) + (s1 - Tv.y) * (s1 - Tv.y) +
                           sc2 * whq + (s4 - 1.0f) * (s4 - 1.0f);
                float lcls = 0.0f;
                for (int cc = 0; cc < 40; cc++) {
                    float s = sigmf_(bf16f(Csb[(chb + 5 + cc) * CS_LD + cc_]));
                    if (cc == ci) { lcls += bce1f(s); l2 += (s - 1.0f) * (s - 1.0f); }
                    else          { lcls += bce0f(s); l2 += s * s; }
                }
                part[3] += lcls; part[4] += l2;
            } else {
                bool objm = !(maxiou > 0.7f);
                if (objm) { part[2] += bce0f(s4); part[4] += s4 * s4; }
            }
        } else {
            if (aidx >= 0) {
                int ci = (int)lb[aidx * 16 + 12];
                float lcls = 0.0f, l2 = 0.0f;
                for (int cc = 40; cc < 80; cc++) {
                    float s = sigmf_(bf16f(Csb[(chb + 5 + cc) * CS_LD + cc_]));
                    if (cc == ci) { lcls += bce1f(s); l2 += (s - 1.0f) * (s - 1.0f); }
                    else          { lcls += bce0f(s); l2 += s * s; }
                }
                part[3] += lcls; part[4] += l2;
            }
        }
    }

#pragma unroll
    for (int i = 0; i < 5; i++) {
        float v = part[i];
        for (int off = 32; off > 0; off >>= 1) v += __shfl_down(v, off);
        if ((t & 63) == 0) red[(t >> 6) * 8 + i] = v;
    }
    __syncthreads();
    if (t == 0) {
#pragma unroll
        for (int i = 0; i < 5; i++) {
            float s = red[i];
#pragma unroll
            for (int wv = 1; wv < 8; wv++) s += red[wv * 8 + i];
            partials[blk * 8 + i] = s;
        }
    }
}

// ---- final reduction ----
__global__ __launch_bounds__(256) void yolo_fin(const float* __restrict__ partials,
                                                float* __restrict__ out, int n) {
    __shared__ float red[4][8];
    const int t = threadIdx.x;
    float s[5] = {0.f, 0.f, 0.f, 0.f, 0.f};
    for (int r = t; r < n; r += 256)
#pragma unroll
        for (int i = 0; i < 5; i++) s[i] += partials[r * 8 + i];
#pragma unroll
    for (int i = 0; i < 5; i++) {
        float v = s[i];
        for (int off = 32; off > 0; off >>= 1) v += __shfl_down(v, off);
        if ((t & 63) == 0) red[t >> 6][i] = v;
    }
    __syncthreads();
    if (t == 0) {
        float xy  = red[0][0] + red[1][0] + red[2][0] + red[3][0];
        float wh  = red[0][1] + red[1][1] + red[2][1] + red[3][1];
        float obj = red[0][2] + red[1][2] + red[2][2] + red[3][2];
        float cls = red[0][3] + red[1][3] + red[2][3] + red[3][3];
        float l2  = red[0][4] + red[1][4] + red[2][4] + red[3][4];
        out[0] = xy + wh + obj + cls;
        out[1] = xy; out[2] = wh; out[3] = obj; out[4] = cls; out[5] = l2;
    }
}

extern "C" void kernel_launch(void* const* d_in, const int* in_sizes, int n_in,
                              void* d_out, int out_size, void* d_ws, size_t ws_size,
                              hipStream_t stream) {
    const float* xin    = (const float*)d_in[0];
    const float* labels = (const float*)d_in[1];
    const float* Wm     = (const float*)d_in[2];
    const float* bias   = (const float*)d_in[3];
    float* out = (float*)d_out;

    float* partials = (float*)d_ws;                            // 46592 B
    float* lrec  = (float*)((char*)d_ws + 46592);              // 40960 B
    u16*   Wbf   = (u16*)((char*)d_ws + 46592 + 40960);        // 131072 B

    yolo_prep<<<257, 256, 0, stream>>>(Wm, labels, Wbf, lrec);
    yolo_mfma<<<NBLK, 512, 0, stream>>>(xin, Wbf, bias, lrec, partials);
    yolo_fin<<<1, 256, 0, stream>>>(partials, out, NBLK);
}

// Round 17
// 70.363 us; speedup vs baseline: 1.0573x; 1.0573x over previous
//
#include <hip/hip_runtime.h>
#include <math.h>

typedef unsigned int u32;
typedef unsigned short u16;
typedef __attribute__((ext_vector_type(4))) u32 u32x4;
typedef __attribute__((ext_vector_type(8))) short bf16x8;
typedef __attribute__((ext_vector_type(4))) float f32x4;

#define FDIM 76
#define NCELL 5776
#define NA 3
#define NCH 85
#define NCLS 80
#define KLAB 40
#define NB 16
#define CIN 256
#define TILES_PER_B 91
#define NBLK (NB * TILES_PER_B)   // 1456
#define CS_LD 68                  // Csb row stride in u16

typedef __attribute__((address_space(1))) const void gvoid_t;
typedef __attribute__((address_space(3))) void svoid_t;

// fast-math helpers (epilogue; tolerance is 2% of 2.4e5)
__device__ __forceinline__ float sigmf_(float x) { return __frcp_rn(1.0f + __expf(-x)); }
__device__ __forceinline__ float bce_fullf(float p, float t) {
    return -(t * fmaxf(__logf(p), -100.0f) + (1.0f - t) * fmaxf(__logf(1.0f - p), -100.0f));
}
__device__ __forceinline__ float bce1f(float p) { return -fmaxf(__logf(p), -100.0f); }
__device__ __forceinline__ float bce0f(float p) { return -fmaxf(__logf(1.0f - p), -100.0f); }

__device__ __forceinline__ u16 bf16rne(float f) {
    u32 u = __float_as_uint(f);
    u32 r = u + 0x7fffu + ((u >> 16) & 1u);
    return (u16)(r >> 16);
}
__device__ __forceinline__ float bf16f(u16 v) { return __uint_as_float(((u32)v) << 16); }

// ---- prep: W fp32->bf16 (blocks 0..255) + label records (block 256) ----
// lrec layout[16]: 0 ttlx 1 ttly 2 tbrx 3 tbry | 4 area 5 valid 6 key 7 scale |
//                  8 tvx 9 tvy 10 tlw 11 tlh | 12 cls 13-15 pad
__global__ __launch_bounds__(256) void yolo_prep(const float* __restrict__ W,
                                                 const float* __restrict__ labels,
                                                 u16* __restrict__ Wbf,
                                                 float* __restrict__ lrec) {
    if (blockIdx.x < 256) {
        int idx = blockIdx.x * 256 + threadIdx.x;
        int row = idx >> 8, col = idx & 255;
        float v = (row < NA * NCH) ? W[row * CIN + col] : 0.0f;
        Wbf[idx] = bf16rne(v);
        return;
    }
    for (int idx = threadIdx.x; idx < NB * KLAB; idx += 256) {
        const float* l = labels + idx * 5;
        float cls = l[0], x = l[1], y = l[2], ww = l[3], hh = l[4];
        bool valid = (cls + x + y + ww + hh) > 0.0f;
        float tx = x * FDIM, ty = y * FDIM, tw = ww * FDIM, th = hh * FDIM;
        int ti = (int)tx, tj = (int)ty;
        float area_a = (tw - tx) * (th - ty);
        const float aw[9] = {1.25f, 2.0f, 4.125f, 3.75f, 7.75f, 7.375f, 14.5f, 19.5f, 46.625f};
        const float ah[9] = {1.625f, 3.75f, 2.875f, 7.625f, 5.625f, 14.875f, 11.25f, 24.75f, 40.75f};
        float best = -1e30f;
        int bi = 0;
        for (int n = 0; n < 9; n++) {
            float bw = fminf(tw, aw[n]), bh = fminf(th, ah[n]);
            float ai = ((tx < bw) && (ty < bh)) ? (bw - tx) * (bh - ty) : 0.0f;
            float iou = valid ? ai / (area_a + aw[n] * ah[n] - ai) : -1.0f;
            if (iou > best) { best = iou; bi = n; }
        }
        int bn = bi % 3;
        bool assign = valid && (bi < 3);
        float* r = lrec + idx * 16;
        r[0] = tx - 0.5f * tw; r[1] = ty - 0.5f * th;
        r[2] = tx + 0.5f * tw; r[3] = ty + 0.5f * th;
        r[4] = tw * th;
        r[5] = valid ? 1.0f : 0.0f;
        r[6] = assign ? (float)((bn * FDIM + tj) * FDIM + ti) : -1.0f;
        r[7] = sqrtf(2.0f - tw * th / (float)(FDIM * FDIM));
        r[8] = tx - (float)ti; r[9] = ty - (float)tj;
        r[10] = logf(tw / aw[bn] + 1e-16f); r[11] = logf(th / ah[bn] + 1e-16f);
        r[12] = cls; r[13] = 0.0f; r[14] = 0.0f; r[15] = 0.0f;
    }
}

// ---- fused GEMM+loss: R14 counted-vmcnt pipeline + T5 setprio around MFMA ----
__global__ __launch_bounds__(512, 6) void yolo_mfma(const float* __restrict__ xin,
                                                    const u16* __restrict__ Wbf,
                                                    const float* __restrict__ bias,
                                                    const float* __restrict__ lrec,
                                                    float* __restrict__ partials) {
    // [0,16384) S0 fp32 [64k][64c] ; [16384,32768) S1 ; [32768,40960) A bf16 [64c][64k] swz
    // epilogue: Csb [256][68] bf16 aliases [0,34816) ; red[8][8] at +40704 (over dead A tail)
    __shared__ char smem[40960];
    float* S0  = (float*)smem;
    float* S1  = (float*)(smem + 16384);
    u16*   A   = (u16*)(smem + 32768);
    u16*   Csb = (u16*)smem;
    float* red = (float*)(smem + 40704);

    const int blk = blockIdx.x;
    const int b = blk / TILES_PER_B;
    const int tile = blk - b * TILES_PER_B;
    const int cell0 = tile * 64;
    const int t = threadIdx.x;
    const int lane = t & 63;
    const int wid = t >> 6;             // 0..7
    const int g = lane >> 4;
    const int l15 = lane & 15;

    const float* xbase = xin + (size_t)b * CIN * NCELL;
    const float* lb = lrec + b * KLAB * 16;          // wave-uniform label records (global)
    const int cg0 = cell0 + lane;
    const int cg = cg0 < NCELL ? cg0 : NCELL - 1;    // clamp; garbage cols masked in epilogue

    // ---- DMA chunk 0 -> S0 (8 insts/wave, fire-and-forget) ----
#pragma unroll
    for (int i = 0; i < 8; i++) {
        const int kl = wid * 8 + i;
        __builtin_amdgcn_global_load_lds(
            (gvoid_t*)(xbase + (size_t)kl * NCELL + cg),
            (svoid_t*)(S0 + kl * 64), 4, 0, 0);
    }

    f32x4 acc[2][4];
#pragma unroll
    for (int mi = 0; mi < 2; mi++)
#pragma unroll
        for (int ni = 0; ni < 4; ni++) acc[mi][ni] = (f32x4){0.f, 0.f, 0.f, 0.f};

    const u16* wrow = Wbf + (wid * 32 + l15) * CIN;   // wave owns channels wid*32..+31

#pragma unroll
    for (int c = 0; c < 4; c++) {
        float* Sc = (c & 1) ? S1 : S0;
        // phase 1a: W fragments for THIS chunk (issued BEFORE next DMA so the
        // compiler's wait for them is vmcnt(8), not a pipeline-draining vmcnt(3))
        bf16x8 af[4];
#pragma unroll
        for (int s2 = 0; s2 < 2; s2++)
#pragma unroll
            for (int mi = 0; mi < 2; mi++)
                af[s2 * 2 + mi] = *(const bf16x8*)(wrow + mi * 16 * CIN + c * 64 + s2 * 32 + g * 8);
        // phase 1b: issue NEXT chunk's DMA (stays in flight across the barrier)
        if (c < 3) {
            float* Sn = (c & 1) ? S0 : S1;
#pragma unroll
            for (int i = 0; i < 8; i++) {
                const int kl = wid * 8 + i;
                __builtin_amdgcn_global_load_lds(
                    (gvoid_t*)(xbase + (size_t)((c + 1) * 64 + kl) * NCELL + cg),
                    (svoid_t*)(Sn + kl * 64), 4, 0, 0);
            }
            // wait: this chunk's DMA + W frags done; next chunk's 8 remain in flight
            asm volatile("s_waitcnt vmcnt(8) lgkmcnt(0)" ::: "memory");
        } else {
            asm volatile("s_waitcnt vmcnt(0) lgkmcnt(0)" ::: "memory");
        }
        __builtin_amdgcn_sched_barrier(0);
        __builtin_amdgcn_s_barrier();
        __builtin_amdgcn_sched_barrier(0);
        // phase 2: convert S[c] fp32 -> A bf16 [64c][64k] swizzled (each elem once)
        {
            const float* sp = Sc + wid * 8 * 64 + lane;   // k = wid*8+e, cell = lane
            u32x4 v;
#pragma unroll
            for (int e = 0; e < 4; e++) {
                float f0 = sp[(2 * e) * 64];
                float f1 = sp[(2 * e + 1) * 64];
                v[e] = (u32)bf16rne(f0) | ((u32)bf16rne(f1) << 16);
            }
            const int byte = (lane * 128 + wid * 16) ^ ((lane & 7) << 4);
            *(u32x4*)((char*)A + byte) = v;
        }
        asm volatile("s_waitcnt lgkmcnt(0)" ::: "memory");
        __builtin_amdgcn_sched_barrier(0);
        __builtin_amdgcn_s_barrier();
        __builtin_amdgcn_sched_barrier(0);
        // phase 3: 8 ds_read_b128 + 16 MFMA (T5: boost wave priority in the cluster)
        __builtin_amdgcn_s_setprio(1);
#pragma unroll
        for (int s2 = 0; s2 < 2; s2++) {
#pragma unroll
            for (int ni = 0; ni < 4; ni++) {
                const int cell = ni * 16 + l15;
                const int byte = (cell * 128 + s2 * 64 + g * 16) ^ ((cell & 7) << 4);
                bf16x8 bfr = *(const bf16x8*)((char*)A + byte);
                acc[0][ni] = __builtin_amdgcn_mfma_f32_16x16x32_bf16(af[s2 * 2 + 0], bfr, acc[0][ni], 0, 0, 0);
                acc[1][ni] = __builtin_amdgcn_mfma_f32_16x16x32_bf16(af[s2 * 2 + 1], bfr, acc[1][ni], 0, 0, 0);
            }
        }
        __builtin_amdgcn_s_setprio(0);
    }

    __syncthreads();    // full drain before Csb aliases S0

    // bias for this thread's 8 output channels
    float bv[8];
#pragma unroll
    for (int mi = 0; mi < 2; mi++)
#pragma unroll
        for (int reg = 0; reg < 4; reg++) {
            const int ch = wid * 32 + mi * 16 + g * 4 + reg;
            bv[mi * 4 + reg] = (ch < NA * NCH) ? bias[ch] : 0.0f;
        }
    // C (+bias) -> LDS bf16 [256][CS_LD]
#pragma unroll
    for (int mi = 0; mi < 2; mi++)
#pragma unroll
        for (int ni = 0; ni < 4; ni++)
#pragma unroll
            for (int reg = 0; reg < 4; reg++) {
                const int ch = wid * 32 + mi * 16 + g * 4 + reg;
                const int cell = ni * 16 + l15;
                Csb[ch * CS_LD + cell] = bf16rne(acc[mi][ni][reg] + bv[mi * 4 + reg]);
            }
    __syncthreads();

    // ---- loss epilogue (verified math; label scan reads GLOBAL lrec, uniform) ----
    float part[5] = {0.f, 0.f, 0.f, 0.f, 0.f};
    if (t < 384) {
        const int half = (t >= 192) ? 1 : 0;
        const int unit = t - half * 192;
        const int a = unit >> 6;
        const int c = unit & 63;
        const int cgl = cell0 + c;
        if (cgl < NCELL) {
            const int chb = a * NCH;
            const int hh = cgl / FDIM;
            const int ww = cgl - hh * FDIM;
            const float mykey = (float)((a * FDIM + hh) * FDIM + ww);
            if (half == 0) {
                float v0 = bf16f(Csb[(chb + 0) * CS_LD + c]);
                float v1 = bf16f(Csb[(chb + 1) * CS_LD + c]);
                float v2 = bf16f(Csb[(chb + 2) * CS_LD + c]);
                float v3 = bf16f(Csb[(chb + 3) * CS_LD + c]);
                float v4 = bf16f(Csb[(chb + 4) * CS_LD + c]);
                const float manw[3] = {1.25f, 2.0f, 4.125f};
                const float manh[3] = {1.625f, 3.75f, 2.875f};
                float s0 = sigmf_(v0), s1 = sigmf_(v1), s4 = sigmf_(v4);
                float pw = __expf(v2) * manw[a];
                float ph = __expf(v3) * manh[a];
                float px = s0 + (float)ww, py = s1 + (float)hh;
                float parea = pw * ph;
                float ptlx = px - 0.5f * pw, ptly = py - 0.5f * ph;
                float pbrx = px + 0.5f * pw, pbry = py + 0.5f * ph;
                float maxiou = -1e30f;
                int aidx = -1;
                for (int k = 0; k < KLAB; k++) {
                    const f32x4 Aq = *(const f32x4*)(lb + k * 16);
                    const f32x4 Bq = *(const f32x4*)(lb + k * 16 + 4);
                    float tlx = fmaxf(ptlx, Aq.x), tly = fmaxf(ptly, Aq.y);
                    float brx = fminf(pbrx, Aq.z), bry = fminf(pbry, Aq.w);
                    float inter = ((tlx < brx) && (tly < bry)) ? (brx - tlx) * (bry - tly) : 0.0f;
                    float iou = (Bq.y != 0.0f) ? inter * __frcp_rn(parea + Bq.x - inter) : 0.0f;
                    maxiou = fmaxf(maxiou, iou);
                    if (Bq.z == mykey) aidx = k;   // last match wins
                }
                if (aidx >= 0) {
                    const f32x4 Bq = *(const f32x4*)(lb + aidx * 16 + 4);
                    const f32x4 Tv = *(const f32x4*)(lb + aidx * 16 + 8);
                    float sc = Bq.w, sc2 = sc * sc;
                    part[0] += sc2 * (bce_fullf(s0, Tv.x) + bce_fullf(s1, Tv.y));
                    float dw = v2 - Tv.z, dh = v3 - Tv.w;
                    float whq = dw * dw + dh * dh;
                    part[1] += 0.5f * sc2 * whq;
                    part[2] += bce1f(s4);
                    int ci = (int)lb[aidx * 16 + 12];
                    float l2 = (s0 - Tv.x) * (s0 - Tv.x) + (s1 - Tv.y) * (s1 - Tv.y) +
                               sc2 * whq + (s4 - 1.0f) * (s4 - 1.0f);
                    float lcls = 0.0f;
                    for (int cc = 0; cc < 40; cc++) {
                        float s = sigmf_(bf16f(Csb[(chb + 5 + cc) * CS_LD + c]));
                        if (cc == ci) { lcls += bce1f(s); l2 += (s - 1.0f) * (s - 1.0f); }
                        else          { lcls += bce0f(s); l2 += s * s; }
                    }
                    part[3] += lcls; part[4] += l2;
                } else {
                    bool objm = !(maxiou > 0.7f);
                    if (objm) { part[2] += bce0f(s4); part[4] += s4 * s4; }
                }
            } else {
                int aidx = -1;
                for (int k = 0; k < KLAB; k++) {
                    if (lb[k * 16 + 6] == mykey) aidx = k;   // last match wins
                }
                if (aidx >= 0) {
                    int ci = (int)lb[aidx * 16 + 12];
                    float lcls = 0.0f, l2 = 0.0f;
                    for (int cc = 40; cc < 80; cc++) {
                        float s = sigmf_(bf16f(Csb[(chb + 5 + cc) * CS_LD + c]));
                        if (cc == ci) { lcls += bce1f(s); l2 += (s - 1.0f) * (s - 1.0f); }
                        else          { lcls += bce0f(s); l2 += s * s; }
                    }
                    part[3] += lcls; part[4] += l2;
                }
            }
        }
    }

#pragma unroll
    for (int i = 0; i < 5; i++) {
        float v = part[i];
        for (int off = 32; off > 0; off >>= 1) v += __shfl_down(v, off);
        if ((t & 63) == 0) red[(t >> 6) * 8 + i] = v;
    }
    __syncthreads();
    if (t == 0) {
#pragma unroll
        for (int i = 0; i < 5; i++) {
            float s = red[i];
#pragma unroll
            for (int wv = 1; wv < 8; wv++) s += red[wv * 8 + i];
            partials[blk * 8 + i] = s;
        }
    }
}

// ---- final reduction ----
__global__ __launch_bounds__(256) void yolo_fin(const float* __restrict__ partials,
                                                float* __restrict__ out, int n) {
    __shared__ float red[4][8];
    const int t = threadIdx.x;
    float s[5] = {0.f, 0.f, 0.f, 0.f, 0.f};
    for (int r = t; r < n; r += 256)
#pragma unroll
        for (int i = 0; i < 5; i++) s[i] += partials[r * 8 + i];
#pragma unroll
    for (int i = 0; i < 5; i++) {
        float v = s[i];
        for (int off = 32; off > 0; off >>= 1) v += __shfl_down(v, off);
        if ((t & 63) == 0) red[t >> 6][i] = v;
    }
    __syncthreads();
    if (t == 0) {
        float xy  = red[0][0] + red[1][0] + red[2][0] + red[3][0];
        float wh  = red[0][1] + red[1][1] + red[2][1] + red[3][1];
        float obj = red[0][2] + red[1][2] + red[2][2] + red[3][2];
        float cls = red[0][3] + red[1][3] + red[2][3] + red[3][3];
        float l2  = red[0][4] + red[1][4] + red[2][4] + red[3][4];
        out[0] = xy + wh + obj + cls;
        out[1] = xy; out[2] = wh; out[3] = obj; out[4] = cls; out[5] = l2;
    }
}

extern "C" void kernel_launch(void* const* d_in, const int* in_sizes, int n_in,
                              void* d_out, int out_size, void* d_ws, size_t ws_size,
                              hipStream_t stream) {
    const float* xin    = (const float*)d_in[0];
    const float* labels = (const float*)d_in[1];
    const float* Wm     = (const float*)d_in[2];
    const float* bias   = (const float*)d_in[3];
    float* out = (float*)d_out;

    float* partials = (float*)d_ws;                            // 46592 B
    float* lrec  = (float*)((char*)d_ws + 46592);              // 40960 B
    u16*   Wbf   = (u16*)((char*)d_ws + 46592 + 40960);        // 131072 B

    yolo_prep<<<257, 256, 0, stream>>>(Wm, labels, Wbf, lrec);
    yolo_mfma<<<NBLK, 512, 0, stream>>>(xin, Wbf, bias, lrec, partials);
    yolo_fin<<<1, 256, 0, stream>>>(partials, out, NBLK);
}